// Round 11
// baseline (464.773 us; speedup 1.0000x reference)
//
#include <hip/hip_runtime.h>

#define N_DIS 25000
#define N_MIR 25000
#define NN    50000
#define E_NUM 600000
#define EMB   128

typedef __attribute__((ext_vector_type(8))) short short8v;   // 8 bf16 payloads (4 VGPR)
typedef __attribute__((ext_vector_type(4))) float floatx4;   // MFMA acc (4 VGPR)

typedef const unsigned int __attribute__((address_space(1))) as1_u32;
typedef unsigned int __attribute__((address_space(3))) as3_u32;

// async global->LDS, 16B per lane, linear LDS dest (wave-uniform base + lane*16).
__device__ __forceinline__ void gld16(const void* g, void* lds) {
    __builtin_amdgcn_global_load_lds((as1_u32*)g, (as3_u32*)lds, 16, 0, 0);
}

// v_mfma_f32_16x16x32_bf16 via inline asm.
__device__ __forceinline__ floatx4 mfma_bf16_16x16x32(short8v a, short8v b, floatx4 c) {
    asm("v_mfma_f32_16x16x32_bf16 %0, %1, %2, %0" : "+v"(c) : "v"(a), "v"(b));
    return c;
}

// bf16 <-> f32 via bit ops (no hip_bf16.h; no bf16 types in any kernel signature)
__device__ __forceinline__ float us2f(unsigned short u) {
    return __uint_as_float(((unsigned)u) << 16);
}
__device__ __forceinline__ unsigned short f2us(float f) {
    unsigned u = __float_as_uint(f);
    unsigned r = ((u >> 16) & 1u) + 0x7FFFu;  // round-to-nearest-even
    u += r;
    return (unsigned short)(u >> 16);
}
__device__ __forceinline__ float loadf(const void* p, size_t i, bool isbf) {
    if (isbf) return us2f(((const unsigned short*)p)[i]);
    return ((const float*)p)[i];
}

// ---------------- init: zero counts + flag ----------------
__global__ __launch_bounds__(256) void gs_zero(int* counts, int* flags) {
    int i = blockIdx.x * blockDim.x + threadIdx.x;
    if (i < NN) counts[i] = 0;
    if (i < 8) flags[i] = 0;
}

__global__ __launch_bounds__(64) void gs_setflag(int* flags, int v) {
    if (threadIdx.x == 0) flags[0] = v;
}

// dtype probe: bf16 data -> low-16 exponent near 127. flags[0] += count.
__global__ __launch_bounds__(256) void gs_probe(const void* x, int* flags) {
    const unsigned* u = (const unsigned*)x;
    unsigned w = u[threadIdx.x];
    int e = (int)((w >> 7) & 0xFF);
    if (e >= 118 && e <= 135) atomicAdd(&flags[0], 1);
}

// ---------------- weight prep: WT[c][k] = split-bf16 of W[k][c], zero-padded to Kp ------
__global__ __launch_bounds__(256) void gs_prepw(const void* Wd, const void* Wm,
                                                const void* Ws1, const void* Wn1,
                                                const void* Ws2, const void* Wn2,
                                                const int* flags, unsigned short* wt) {
    const bool isbf = flags[0] > 128;
    const int t = threadIdx.x;
    const int w = blockIdx.x >> 2;
    const int cq = (blockIdx.x & 3) * 32;
    const void* W;
    unsigned short* oh;
    unsigned short* ol;
    int K, Kp;
    if (w == 0)      { W = Wd;  oh = wt + 0;      ol = wt + 49152;  K = 383; Kp = 384; }
    else if (w == 1) { W = Wm;  oh = wt + 98304;  ol = wt + 163840; K = 495; Kp = 512; }
    else if (w == 2) { W = Ws1; oh = wt + 229376; ol = wt + 245760; K = 128; Kp = 128; }
    else if (w == 3) { W = Wn1; oh = wt + 262144; ol = wt + 278528; K = 128; Kp = 128; }
    else if (w == 4) { W = Ws2; oh = wt + 294912; ol = wt + 311296; K = 128; Kp = 128; }
    else             { W = Wn2; oh = wt + 327680; ol = wt + 344064; K = 128; Kp = 128; }
    for (int c = cq; c < cq + 32; ++c) {
        for (int k = t; k < Kp; k += 256) {
            float x = (k < K) ? loadf(W, (size_t)k * EMB + c, isbf) : 0.f;
            unsigned short h = f2us(x);
            oh[(size_t)c * Kp + k] = h;
            ol[(size_t)c * Kp + k] = f2us(x - us2f(h));
        }
    }
}

// ---------------- CSR build ----------------
__global__ __launch_bounds__(256) void gs_count(const int* dst, int* counts) {
    int e = blockIdx.x * blockDim.x + threadIdx.x;
    if (e < E_NUM) {
        unsigned d = (unsigned)dst[e];
        if (d < (unsigned)NN) atomicAdd(&counts[d], 1);
    }
}

__global__ __launch_bounds__(256) void gs_scan1(const int* counts, int* row_start, int* bsums) {
    __shared__ int tsum[256];
    const int t = threadIdx.x;
    const int base = blockIdx.x * 1024 + t * 4;
    int v0 = (base + 0 < NN) ? counts[base + 0] : 0;
    int v1 = (base + 1 < NN) ? counts[base + 1] : 0;
    int v2 = (base + 2 < NN) ? counts[base + 2] : 0;
    int v3 = (base + 3 < NN) ? counts[base + 3] : 0;
    int s = v0 + v1 + v2 + v3;
    tsum[t] = s;
    __syncthreads();
    for (int off = 1; off < 256; off <<= 1) {
        int xv = 0;
        if (t >= off) xv = tsum[t - off];
        __syncthreads();
        tsum[t] += xv;
        __syncthreads();
    }
    int excl = tsum[t] - s;
    if (base + 0 < NN) row_start[base + 0] = excl;
    excl += v0;
    if (base + 1 < NN) row_start[base + 1] = excl;
    excl += v1;
    if (base + 2 < NN) row_start[base + 2] = excl;
    excl += v2;
    if (base + 3 < NN) row_start[base + 3] = excl;
    if (t == 255) bsums[blockIdx.x] = tsum[255];
}

__global__ __launch_bounds__(64) void gs_scan2(int* bsums, int* row_start, int nb) {
    if (threadIdx.x == 0) {
        int run = 0;
        for (int i = 0; i < nb; ++i) {
            int v = bsums[i];
            bsums[i] = run;
            run += v;
        }
        row_start[NN] = run;
    }
}

__global__ __launch_bounds__(256) void gs_scan3(int* row_start, int* cursor, const int* bsums) {
    const int t = threadIdx.x;
    const int base = blockIdx.x * 1024 + t * 4;
    const int add = bsums[blockIdx.x];
    for (int i = 0; i < 4; ++i) {
        int idx = base + i;
        if (idx < NN) {
            int v = row_start[idx] + add;
            row_start[idx] = v;
            cursor[idx] = v;
        }
    }
}

__global__ __launch_bounds__(256) void gs_scatter(const int* src, const int* dst, int* cursor,
                                                  int* eidx) {
    int e = blockIdx.x * blockDim.x + threadIdx.x;
    if (e < E_NUM) {
        unsigned d = (unsigned)dst[e];
        unsigned sv = (unsigned)src[e];
        if (d < (unsigned)NN && sv < (unsigned)NN) {
            int p = atomicAdd(&cursor[d], 1);
            eidx[p] = (int)sv;
        }
    }
}

// ------- mean aggregation over split-bf16 planes (16B vectorized, 16 lanes/row) -------
__global__ __launch_bounds__(256) void gs_aggp(const unsigned short* __restrict__ xh,
                                               const unsigned short* __restrict__ xl,
                                               const int* __restrict__ row_start,
                                               const int* __restrict__ eidx,
                                               unsigned short* __restrict__ oh,
                                               unsigned short* __restrict__ ol) {
    const int t = threadIdx.x;
    const int row = blockIdx.x * 16 + (t >> 4);
    const int c8 = (t & 15) * 8;
    if (row >= NN) return;
    const int s0 = row_start[row];
    const int s1 = row_start[row + 1];
    float a[8], b[8];
#pragma unroll
    for (int j = 0; j < 8; ++j) { a[j] = 0.f; b[j] = 0.f; }
    int e = s0;
    for (; e + 1 < s1; e += 2) {
        const int sa = eidx[e];
        const int sb = eidx[e + 1];
        short8v ha = *(const short8v*)&xh[(size_t)sa * EMB + c8];
        short8v la = *(const short8v*)&xl[(size_t)sa * EMB + c8];
        short8v hb = *(const short8v*)&xh[(size_t)sb * EMB + c8];
        short8v lb = *(const short8v*)&xl[(size_t)sb * EMB + c8];
#pragma unroll
        for (int j = 0; j < 8; ++j) {
            a[j] += us2f((unsigned short)ha[j]) + us2f((unsigned short)la[j]);
            b[j] += us2f((unsigned short)hb[j]) + us2f((unsigned short)lb[j]);
        }
    }
    if (e < s1) {
        const int sa = eidx[e];
        short8v ha = *(const short8v*)&xh[(size_t)sa * EMB + c8];
        short8v la = *(const short8v*)&xl[(size_t)sa * EMB + c8];
#pragma unroll
        for (int j = 0; j < 8; ++j)
            a[j] += us2f((unsigned short)ha[j]) + us2f((unsigned short)la[j]);
    }
    const float inv = (s1 > s0) ? 1.f / (float)(s1 - s0) : 0.f;
    short8v vh, vl;
#pragma unroll
    for (int j = 0; j < 8; ++j) {
        const float f = (a[j] + b[j]) * inv;
        const unsigned short h = f2us(f);
        vh[j] = (short)h;
        vl[j] = (short)f2us(f - us2f(h));
    }
    *(short8v*)&oh[(size_t)row * EMB + c8] = vh;
    *(short8v*)&ol[(size_t)row * EMB + c8] = vl;
}

// =============== BM=64 x BN=64 MFMA GEMMs, slim dynamic LDS, high-occupancy ===============
// 256 thr = 4 waves (2x2): wave = 32 rows x 32 cols (acc[2][2]). KC=64.
// LDS (dynamic): slim(bf16-known): mmp {XH 8K, WH 8K}=16K; mml {XH 8K, XL 8K, WH 8K}=24K.
//                full: {XH 8K, XL 8K, WH 8K, WL 8K}=32K.
// Byte swizzle (round-5-proven, 0 conflicts): content byte kb of row r at kb ^ ((r&7)<<4).

// ---------------- proj: features @ W -> split planes ----------------
__global__ __launch_bounds__(256, 6) void gs_mmp(
    const void* __restrict__ Xa, int Ka, const unsigned short* __restrict__ WAh,
    const unsigned short* __restrict__ WAl, int KpA, const void* __restrict__ ba,
    const void* __restrict__ Xb, int Kb, const unsigned short* __restrict__ WBh,
    const unsigned short* __restrict__ WBl, int KpB, const void* __restrict__ bb,
    int splitB, int Ma, int Mb, int slim,
    const int* __restrict__ flags, unsigned short* __restrict__ outH,
    unsigned short* __restrict__ outL) {
    extern __shared__ __align__(16) unsigned char sm[];
    const int xlOff = 8192;                       // full layout only
    const int whOff = slim ? 8192 : 16384;
    const int wlOff = 24576;                      // full layout only
    const bool isbf = flags[0] > 128;
    const int t = threadIdx.x;
    const bool sideB = (int)blockIdx.x >= splitB;
    const int b2 = sideB ? ((int)blockIdx.x - splitB) : (int)blockIdx.x;
    const void* X1 = sideB ? Xb : Xa;
    const unsigned short* W1h = sideB ? WBh : WAh;
    const unsigned short* W1l = sideB ? WBl : WAl;
    const int K1 = sideB ? Kb : Ka;
    const int Kp1 = sideB ? KpB : KpA;
    const void* bias = sideB ? bb : ba;
    const int M = sideB ? Mb : Ma;
    const int r0 = (b2 >> 1) * 64;
    const int c0 = (b2 & 1) * 64;
    unsigned short* oh = outH + (sideB ? (size_t)Ma * EMB : 0);
    unsigned short* ol = outL + (sideB ? (size_t)Ma * EMB : 0);
    const bool xbf = isbf;  // features share input dtype

    const int l = t & 63;
    const int wv = t >> 6;                // 0..3
    const int wr = wv >> 1, wc = wv & 1;  // 2x2 wave grid, 32x32 tiles
    const int lr = l & 15, lg = l >> 4;

    floatx4 acc[2][2];
#pragma unroll
    for (int rt = 0; rt < 2; ++rt)
#pragma unroll
        for (int ct = 0; ct < 2; ++ct) acc[rt][ct] = (floatx4){0.f, 0.f, 0.f, 0.f};

    const int nch = (K1 + 63) >> 6;
    const int srX = t >> 2;          // X stage: row 0..63
    const int k8 = (t & 3) << 4;     // X stage: k base (16 k per thread)
    const int swz = (srX & 7) << 4;
    const int rel0 = (srX << 7) + ((((t & 3) << 5) + 0) ^ swz);
    const int rel1 = (srX << 7) + ((((t & 3) << 5) + 16) ^ swz);

    for (int ch = 0; ch < nch; ++ch) {
        const int ck0 = ch << 6;
        __syncthreads();  // previous chunk's compute fully consumed LDS

        // ---- W stage: gld16, pre-swizzled src, 64 cols x 128B = 8KB/plane (2/thread) ----
#pragma unroll
        for (int i = 0; i < 2; ++i) {
            const int p = (i * 256 + t) << 4;  // [0, 8192)
            const int cl = p >> 7;
            const int g16 = p & 0x7F;
            const size_t so =
                ((size_t)(c0 + cl) * Kp1 + ck0) * 2 + (size_t)(g16 ^ ((cl & 7) << 4));
            gld16((const unsigned char*)W1h + so, sm + whOff + p);
            if (!isbf) gld16((const unsigned char*)W1l + so, sm + wlOff + p);
        }

        // ---- X stage ----
        const int gr = r0 + srX;
        if (xbf) {
            // 9 aligned-dword loads + funnel shift (rows are only 2B-aligned for odd K1)
            unsigned d[9];
            const size_t base = (size_t)gr * ((size_t)K1 << 1) + (size_t)((ck0 + k8) << 1);
            const size_t a0 = base & ~(size_t)3;
            const unsigned sh = (unsigned)(base & 3) << 3;  // 0 or 16
            if (gr < M) {
#pragma unroll
                for (int k = 0; k < 9; ++k)
                    d[k] = *(const unsigned*)((const unsigned char*)X1 + a0 + ((size_t)k << 2));
            } else {
#pragma unroll
                for (int k = 0; k < 9; ++k) d[k] = 0u;
            }
            unsigned e4[8];
#pragma unroll
            for (int k = 0; k < 8; ++k)
                e4[k] = sh ? ((d[k] >> sh) | (d[k + 1] << (32 - sh))) : d[k];
            short8v v0, v1;
#pragma unroll
            for (int j = 0; j < 8; ++j) {
                const int gk = ck0 + k8 + j;
                const unsigned s = (j & 1) ? (e4[j >> 1] >> 16) : (e4[j >> 1] & 0xFFFFu);
                v0[j] = (short)((gk < K1) ? s : 0u);
            }
#pragma unroll
            for (int j = 0; j < 8; ++j) {
                const int jj = 8 + j;
                const int gk = ck0 + k8 + jj;
                const unsigned s = (jj & 1) ? (e4[jj >> 1] >> 16) : (e4[jj >> 1] & 0xFFFFu);
                v1[j] = (short)((gk < K1) ? s : 0u);
            }
            *(short8v*)(sm + rel0) = v0;
            *(short8v*)(sm + rel1) = v1;
        } else {
            // f32: 16 guarded dword loads + trunc split -> hi/lo planes
            unsigned xu[16];
#pragma unroll
            for (int j = 0; j < 16; ++j) {
                const int gk = ck0 + k8 + j;
                unsigned v = 0u;
                if (gr < M && gk < K1) v = ((const unsigned*)X1)[(size_t)gr * K1 + gk];
                xu[j] = v;
            }
#pragma unroll
            for (int g = 0; g < 2; ++g) {
                short8v vh, vl;
#pragma unroll
                for (int e = 0; e < 8; ++e) {
                    const unsigned u = xu[(g << 3) + e];
                    const unsigned short h = (unsigned short)(u >> 16);
                    vh[e] = (short)h;
                    vl[e] = (short)f2us(__uint_as_float(u) - us2f(h));
                }
                const int rel = g ? rel1 : rel0;
                *(short8v*)(sm + rel) = vh;
                *(short8v*)(sm + xlOff + rel) = vl;
            }
        }
        __syncthreads();  // drains vmcnt (gld16) + lgkm (ds_writes)

        // ---- compute: 2 k-steps x (2 rt x 2 ct) x split terms ----
#pragma unroll
        for (int ks = 0; ks < 2; ++ks) {
            const int kb = (ks << 6) + (lg << 4);
            short8v ah[2], al[2];
#pragma unroll
            for (int rt = 0; rt < 2; ++rt) {
                const int row = wr * 32 + rt * 16 + lr;
                const int rel = (row << 7) + (kb ^ ((row & 7) << 4));
                ah[rt] = *(const short8v*)(sm + rel);
                if (!xbf) al[rt] = *(const short8v*)(sm + xlOff + rel);
            }
#pragma unroll
            for (int ct = 0; ct < 2; ++ct) {
                const int cl = wc * 32 + ct * 16 + lr;
                const int brel = (cl << 7) + (kb ^ ((cl & 7) << 4));
                short8v bh = *(const short8v*)(sm + whOff + brel);
#pragma unroll
                for (int rt = 0; rt < 2; ++rt)
                    acc[rt][ct] = mfma_bf16_16x16x32(ah[rt], bh, acc[rt][ct]);
                if (!xbf) {
#pragma unroll
                    for (int rt = 0; rt < 2; ++rt)
                        acc[rt][ct] = mfma_bf16_16x16x32(al[rt], bh, acc[rt][ct]);
                }
                if (!isbf) {
                    short8v bl = *(const short8v*)(sm + wlOff + brel);
#pragma unroll
                    for (int rt = 0; rt < 2; ++rt)
                        acc[rt][ct] = mfma_bf16_16x16x32(ah[rt], bl, acc[rt][ct]);
                }
            }
        }
    }

    // ---- epilogue: split planes; D map j=lane&15, i=4*(lane>>4)+reg ----
#pragma unroll
    for (int ct = 0; ct < 2; ++ct) {
        const int col = c0 + wc * 32 + ct * 16 + lr;
        const float bbv = loadf(bias, col, isbf);
#pragma unroll
        for (int rt = 0; rt < 2; ++rt) {
#pragma unroll
            for (int rr = 0; rr < 4; ++rr) {
                const int row = r0 + wr * 32 + rt * 16 + (lg << 2) + rr;
                if (row < M) {
                    const float v = acc[rt][ct][rr] + bbv;
                    const unsigned short h = f2us(v);
                    oh[(size_t)row * EMB + col] = h;
                    ol[(size_t)row * EMB + col] = f2us(v - us2f(h));
                }
            }
        }
    }
}

// ---------------- layers: plane-X @ plane-W (+X2@W2), pure-DMA staging ----------------
__global__ __launch_bounds__(256, 6) void gs_mml(
    const unsigned short* __restrict__ X1h, const unsigned short* __restrict__ X1l,
    const unsigned short* __restrict__ W1h, const unsigned short* __restrict__ W1l,
    const unsigned short* __restrict__ X2h, const unsigned short* __restrict__ X2l,
    const unsigned short* __restrict__ W2h, const unsigned short* __restrict__ W2l,
    const void* __restrict__ bias, const int* __restrict__ flags, int slim,
    float* __restrict__ outf, unsigned short* __restrict__ outh,
    unsigned short* __restrict__ outl, int do_relu) {
    extern __shared__ __align__(16) unsigned char sm[];
    const int xlOff = 8192;
    const int whOff = 16384;
    const int wlOff = 24576;  // full layout only
    const bool isbf = flags[0] > 128;  // W lo plane is zero -> skip
    const int t = threadIdx.x;
    const int r0 = ((int)blockIdx.x >> 1) * 64;
    const int c0 = ((int)blockIdx.x & 1) * 64;
    const int l = t & 63;
    const int wv = t >> 6;                // 0..3
    const int wr = wv >> 1, wc = wv & 1;  // 2x2 wave grid, 32x32 tiles
    const int lr = l & 15, lg = l >> 4;

    floatx4 acc[2][2];
#pragma unroll
    for (int rt = 0; rt < 2; ++rt)
#pragma unroll
        for (int ct = 0; ct < 2; ++ct) acc[rt][ct] = (floatx4){0.f, 0.f, 0.f, 0.f};

    const int nst = slim ? 6 : 8;  // gld16 rounds: XH,XL,WH(,WL) x 8KB / (256x16B) = 2 each

    for (int ch = 0; ch < 4; ++ch) {
        const unsigned short* xh = (ch < 2) ? X1h : X2h;
        const unsigned short* xl = (ch < 2) ? X1l : X2l;
        const unsigned short* wh = (ch < 2) ? W1h : W2h;
        const unsigned short* wl = (ch < 2) ? W1l : W2l;
        const int ck0b = (ch & 1) << 7;  // k-chunk byte offset (64 bf16 = 128 B)

        __syncthreads();
        for (int i = 0; i < nst; ++i) {
            const int idx = i * 256 + t;
            const int reg = idx >> 9;          // 0:XH 1:XL 2:WH 3:WL
            const int p = (idx & 511) << 4;    // [0, 8192) within plane
            const int rc = p >> 7;
            const int g16 = p & 0x7F;
            const int off = g16 ^ ((rc & 7) << 4);
            if (reg == 0) {
                const int gr = (r0 + rc < NN) ? (r0 + rc) : (NN - 1);
                gld16((const unsigned char*)xh + (size_t)gr * 256 + ck0b + off, sm + p);
            } else if (reg == 1) {
                const int gr = (r0 + rc < NN) ? (r0 + rc) : (NN - 1);
                gld16((const unsigned char*)xl + (size_t)gr * 256 + ck0b + off,
                      sm + xlOff + p);
            } else if (reg == 2) {
                gld16((const unsigned char*)wh + (size_t)(c0 + rc) * 256 + ck0b + off,
                      sm + whOff + p);
            } else {
                gld16((const unsigned char*)wl + (size_t)(c0 + rc) * 256 + ck0b + off,
                      sm + wlOff + p);
            }
        }
        __syncthreads();  // drains vmcnt(0)

        // compute: 2 k-steps x (2 rt x 2 ct) x {Xh,Xl} (+Wl term when f32)
#pragma unroll
        for (int ks = 0; ks < 2; ++ks) {
            const int kb = (ks << 6) + (lg << 4);
            short8v ah[2], al[2];
#pragma unroll
            for (int rt = 0; rt < 2; ++rt) {
                const int row = wr * 32 + rt * 16 + lr;
                const int rel = (row << 7) + (kb ^ ((row & 7) << 4));
                ah[rt] = *(const short8v*)(sm + rel);
                al[rt] = *(const short8v*)(sm + xlOff + rel);
            }
#pragma unroll
            for (int ct = 0; ct < 2; ++ct) {
                const int cl = wc * 32 + ct * 16 + lr;
                const int brel = (cl << 7) + (kb ^ ((cl & 7) << 4));
                short8v bh = *(const short8v*)(sm + whOff + brel);
#pragma unroll
                for (int rt = 0; rt < 2; ++rt) {
                    acc[rt][ct] = mfma_bf16_16x16x32(ah[rt], bh, acc[rt][ct]);
                    acc[rt][ct] = mfma_bf16_16x16x32(al[rt], bh, acc[rt][ct]);
                }
                if (!isbf) {
                    short8v bl = *(const short8v*)(sm + wlOff + brel);
#pragma unroll
                    for (int rt = 0; rt < 2; ++rt)
                        acc[rt][ct] = mfma_bf16_16x16x32(ah[rt], bl, acc[rt][ct]);
                }
            }
        }
    }

    // epilogue
#pragma unroll
    for (int ct = 0; ct < 2; ++ct) {
        const int col = c0 + wc * 32 + ct * 16 + lr;
        const float bbv = loadf(bias, col, isbf);
#pragma unroll
        for (int rt = 0; rt < 2; ++rt) {
#pragma unroll
            for (int rr = 0; rr < 4; ++rr) {
                const int row = r0 + wr * 32 + rt * 16 + (lg << 2) + rr;
                if (row < NN) {
                    float v = acc[rt][ct][rr] + bbv;
                    if (do_relu) v = v > 0.f ? v : 0.f;
                    if (outf) {
                        outf[(size_t)row * EMB + col] = v;
                    } else {
                        const unsigned short h = f2us(v);
                        outh[(size_t)row * EMB + col] = h;
                        outl[(size_t)row * EMB + col] = f2us(v - us2f(h));
                    }
                }
            }
        }
    }
}

extern "C" __attribute__((visibility("default"))) void kernel_launch(
    void* const* d_in, const int* in_sizes, int n_in, void* d_out, int out_size, void* d_ws,
    size_t ws_size, hipStream_t stream) {
    // ---- ordering + dtype from in_sizes[0] (d_features in dict order, W_d if sorted) ----
    int iDF = 0, iMF = 1, iSRC = 2, iDST = 3, iWD = 4, iBD = 5, iWM = 6, iBM = 7;
    int iWS1 = 8, iWN1 = 9, iB1 = 10, iWS2 = 11, iWN2 = 12, iB2 = 13;
    long u0 = in_sizes ? (long)in_sizes[0] : 9575000L;
    int dt = -1;  // -1 unknown (probe), 0 f32, 1 bf16
    if (u0 == 49024L || u0 == 98048L || u0 == 196096L) {
        iWD = 0; iWM = 1; iWN1 = 2; iWN2 = 3; iWS1 = 4; iWS2 = 5;
        iB1 = 6; iB2 = 7; iBD = 8; iBM = 9; iDF = 10; iDST = 11; iMF = 12; iSRC = 13;
        if (u0 == 98048L) dt = 1;
        else if (u0 == 196096L) dt = 0;
    } else {
        if (u0 == 19150000L) dt = 1;       // bytes, bf16
        else if (u0 == 38300000L) dt = 0;  // bytes, f32
    }
    const void* d_features = d_in[iDF];
    const void* m_features = d_in[iMF];
    const int* src = (const int*)d_in[iSRC];
    const int* dst = (const int*)d_in[iDST];
    const void* W_d = d_in[iWD];
    const void* b_d = d_in[iBD];
    const void* W_m = d_in[iWM];
    const void* b_m = d_in[iBM];
    const void* W_self1 = d_in[iWS1];
    const void* W_neigh1 = d_in[iWN1];
    const void* b1 = d_in[iB1];
    const void* W_self2 = d_in[iWS2];
    const void* W_neigh2 = d_in[iWN2];
    const void* b2v = d_in[iB2];

    const int slim = (dt == 1) ? 1 : 0;  // host-known bf16 -> drop dead lo-planes from LDS

    // ---- workspace layout (54,921,344 B — unchanged from round 8) ----
    char* w = (char*)d_ws;
    int* flags = (int*)(w + 0);            //        64 B
    int* counts = (int*)(w + 64);          //   200,000 B
    int* row_start = (int*)(w + 200064);   //   200,004 B (pad to 400128)
    int* cursor = (int*)(w + 400128);      //   200,000 B
    int* bsums = (int*)(w + 600128);       //       256 B
    int* eidx = (int*)(w + 600384);        // 2,400,000 B (pad to 3000448)
    unsigned short* wt = (unsigned short*)(w + 3000448);  // 720,896 B split-bf16 WT panels
    unsigned short* wt_hd = wt + 0;
    unsigned short* wt_ld = wt + 49152;
    unsigned short* wt_hm = wt + 98304;
    unsigned short* wt_lm = wt + 163840;
    unsigned short* wt_hs1 = wt + 229376;
    unsigned short* wt_ls1 = wt + 245760;
    unsigned short* wt_hn1 = wt + 262144;
    unsigned short* wt_ln1 = wt + 278528;
    unsigned short* wt_hs2 = wt + 294912;
    unsigned short* wt_ls2 = wt + 311296;
    unsigned short* wt_hn2 = wt + 327680;
    unsigned short* wt_ln2 = wt + 344064;
    // hF / h1F as split bf16 plane pairs (12.8 MB each plane)
    unsigned short* hFh = (unsigned short*)(w + 3721344);    // 12,800,000 B
    unsigned short* hFl = (unsigned short*)(w + 16521344);   // 12,800,000 B
    unsigned short* h1Fh = (unsigned short*)(w + 29321344);  // 12,800,000 B
    unsigned short* h1Fl = (unsigned short*)(w + 42121344);  // 12,800,000 B -> 54,921,344
    // agg planes: agg1 -> d_out (dead before final write); agg2 -> hF region (dead after L1)
    unsigned short* ag1h = (unsigned short*)d_out;
    unsigned short* ag1l = ag1h + 6400000;
    unsigned short* ag2h = hFh;
    unsigned short* ag2l = hFl;

    const int NB_SCAN = (NN + 1023) / 1024;  // 49
    const int EB = (E_NUM + 255) / 256;      // 2344
    const int ZB = (NN + 255) / 256;         // 196

    // init + dtype resolution (flags[0] > 128 => bf16)
    hipLaunchKernelGGL(gs_zero, dim3(ZB), dim3(256), 0, stream, counts, flags);
    if (dt == 1)
        hipLaunchKernelGGL(gs_setflag, dim3(1), dim3(64), 0, stream, flags, 1000);
    else if (dt == 0)
        hipLaunchKernelGGL(gs_setflag, dim3(1), dim3(64), 0, stream, flags, 0);
    else
        hipLaunchKernelGGL(gs_probe, dim3(1), dim3(256), 0, stream, d_features, flags);

    // weight prep
    hipLaunchKernelGGL(gs_prepw, dim3(24), dim3(256), 0, stream, W_d, W_m, W_self1, W_neigh1,
                       W_self2, W_neigh2, flags, wt);

    // CSR build
    hipLaunchKernelGGL(gs_count, dim3(EB), dim3(256), 0, stream, dst, counts);
    hipLaunchKernelGGL(gs_scan1, dim3(NB_SCAN), dim3(256), 0, stream, counts, row_start, bsums);
    hipLaunchKernelGGL(gs_scan2, dim3(1), dim3(64), 0, stream, bsums, row_start, NB_SCAN);
    hipLaunchKernelGGL(gs_scan3, dim3(NB_SCAN), dim3(256), 0, stream, row_start, cursor, bsums);
    hipLaunchKernelGGL(gs_scatter, dim3(EB), dim3(256), 0, stream, src, dst, cursor, eidx);

    // projections (one dispatch, block-split, BM=64 x BN=64) -> hF planes
    const int PBd = (N_DIS + 63) / 64;    // 391 row-blocks per side
    const int SPLIT = 2 * PBd;            // 782 (side A: 391 rows x 2 col-halves)
    const size_t shP = slim ? 16384 : 32768;
    hipLaunchKernelGGL(gs_mmp, dim3(2 * SPLIT), dim3(256), shP, stream,
                       d_features, 383, wt_hd, wt_ld, 384, b_d,
                       m_features, 495, wt_hm, wt_lm, 512, b_m,
                       SPLIT, N_DIS, N_MIR, slim, flags, hFh, hFl);

    const int AB = NN / 16;               // 3125
    const int GBL = ((NN + 63) / 64) * 2; // 782 row-blocks x 2 col-halves = 1564
    const size_t shL = slim ? 24576 : 32768;

    // layer 1: agg(hF planes) -> d_out planes; h1F planes = relu(hF@Ws1 + agg@Wn1 + b1)
    hipLaunchKernelGGL(gs_aggp, dim3(AB), dim3(256), 0, stream, hFh, hFl, row_start, eidx,
                       ag1h, ag1l);
    hipLaunchKernelGGL(gs_mml, dim3(GBL), dim3(256), shL, stream,
                       hFh, hFl, wt_hs1, wt_ls1, ag1h, ag1l, wt_hn1, wt_ln1,
                       b1, flags, slim, (float*)nullptr, h1Fh, h1Fl, 1);

    // layer 2: agg(h1F planes) -> hF region planes; d_out = h1F@Ws2 + agg@Wn2 + b2 (f32)
    hipLaunchKernelGGL(gs_aggp, dim3(AB), dim3(256), 0, stream, h1Fh, h1Fl, row_start, eidx,
                       ag2h, ag2l);
    hipLaunchKernelGGL(gs_mml, dim3(GBL), dim3(256), shL, stream,
                       h1Fh, h1Fl, wt_hs2, wt_ls2, ag2h, ag2l, wt_hn2, wt_ln2,
                       b2v, flags, slim, (float*)d_out, (unsigned short*)nullptr,
                       (unsigned short*)nullptr, 0);
}